// Round 8
// baseline (295.993 us; speedup 1.0000x reference)
//
#include <hip/hip_runtime.h>
#include <cstddef>
#include <cstdint>

// Problem constants: B=2, T=2048, C=1024, H=16, hs=64
#define B_N 2
#define T_N 2048
#define C_N 1024
#define H_N 16
#define HS_N 64
#define M_N (B_N * T_N)   // 4096

typedef __attribute__((ext_vector_type(8))) short bf16x8;   // 8 bf16 = 4 VGPRs
typedef __attribute__((ext_vector_type(4))) float f32x4;

// 0.125 (hs^-0.5) * log2(e): folded into Wq so attention uses exp2 directly
#define QSCALE 0.18033688011112042f

__device__ __forceinline__ ushort f2bf(float f) {
    union { float f; uint32_t u; } v; v.f = f;
    uint32_t r = v.u + 0x7fffu + ((v.u >> 16) & 1u);   // round-nearest-even
    return (ushort)(r >> 16);
}

// ---------------------------------------------------------------------------
// Fused fp32->bf16 convert: x | Wq(*QSCALE) | Wp | Wk | Wv (one launch).
// ---------------------------------------------------------------------------
__global__ void cvt_all_kernel(const float* __restrict__ x,
                               const float* __restrict__ Wq,
                               const float* __restrict__ Wp,
                               const float* __restrict__ Wk,
                               const float* __restrict__ Wv,
                               ushort* __restrict__ xb,
                               ushort* __restrict__ Wqb,
                               ushort* __restrict__ Wpb,
                               ushort* __restrict__ Wkvb) {
    const int S0 = M_N * C_N / 4;
    const int S1 = S0 + C_N * C_N / 4;
    const int S2 = S1 + C_N * C_N / 4;
    const int S3 = S2 + HS_N * C_N / 4;
    const int S4 = S3 + HS_N * C_N / 4;
    const int stride = gridDim.x * blockDim.x;
    for (int i = blockIdx.x * blockDim.x + threadIdx.x; i < S4; i += stride) {
        const float* src; ushort* dst; int j; float sc = 1.f;
        if (i < S0)      { src = x;  dst = xb;   j = i; }
        else if (i < S1) { src = Wq; dst = Wqb;  j = i - S0; sc = QSCALE; }
        else if (i < S2) { src = Wp; dst = Wpb;  j = i - S1; }
        else if (i < S3) { src = Wk; dst = Wkvb; j = i - S2; }
        else             { src = Wv; dst = Wkvb + HS_N * C_N; j = i - S3; }
        const float4 f = ((const float4*)src)[j];
        ushort4 o;
        o.x = f2bf(f.x * sc); o.y = f2bf(f.y * sc);
        o.z = f2bf(f.z * sc); o.w = f2bf(f.w * sc);
        ((ushort4*)dst)[j] = o;
    }
}

// ---------------------------------------------------------------------------
// bf16 MFMA GEMM, DIRECT GLOBAL->REGISTER (no LDS, no barriers).
// Every MFMA fragment at this tiling is a lane-contiguous 16B global load:
//   A-frag row m0+wm*32+i*16+ln, cols k0+hh*32+quad*8  (rows 2KB apart)
//   B-frag row n0+wn*64+j*16+ln, same cols
// LDS staging only gave 2x reuse (L1 provides that) but cost 2 barriers +
// a vmcnt(0) drain per K-iter — the structural ~200TF wall of rounds 4-7.
// K templated -> K-loop fully unrolled: 192 loads + 256 mfma interleaved by
// the compiler with fine-grained vmcnt (AITER-style), loads stay in flight.
// BM=64, BN=128, 4 waves 2x2 (wave 32x64). Grid 576/512 blocks.
// MODE 0: fp32 out + bias. MODE 1: bf16 out; 9th n-tile -> kb natural +
// vbt transposed [b][d][t] (packed ushort4 = 4 consecutive t).
// ---------------------------------------------------------------------------
template <int MODE, int K>
__global__ __launch_bounds__(256, 2) void gemm_bf16(
    const ushort* __restrict__ A,   // [M][K] bf16
    const ushort* __restrict__ W,   // [Ntot][K] bf16
    const float* __restrict__ bias, // MODE 0 only
    void* __restrict__ Cout,        // [M][1024] fp32 (MODE 0) / bf16 (MODE 1)
    ushort* __restrict__ kb,        // MODE 1: [4096][64]
    ushort* __restrict__ vbt)       // MODE 1: [2][64][2048]
{
    const int m0 = blockIdx.x * 64;
    const int n0 = blockIdx.y * 128;
    const int tid = threadIdx.x;
    const int wid = tid >> 6;
    const int lane = tid & 63;
    const int ln = lane & 15;
    const int quad = lane >> 4;
    const int wm = wid >> 1, wn = wid & 1;   // wave = rows wm*32+, cols wn*64+

    f32x4 acc[2][4];
    #pragma unroll
    for (int i = 0; i < 2; ++i)
        #pragma unroll
        for (int j = 0; j < 4; ++j)
            acc[i][j] = (f32x4){0.f, 0.f, 0.f, 0.f};

    const ushort* Abase = A + (size_t)(m0 + wm * 32 + ln) * K + quad * 8;
    const ushort* Wbase = W + (size_t)(n0 + wn * 64 + ln) * K + quad * 8;

    #pragma unroll
    for (int k0 = 0; k0 < K; k0 += 64) {
        bf16x8 af[2][2], bf[4][2];
        #pragma unroll
        for (int i = 0; i < 2; ++i)
            #pragma unroll
            for (int hh = 0; hh < 2; ++hh)
                af[i][hh] = *(const bf16x8*)(Abase + (size_t)i * 16 * K
                                             + k0 + hh * 32);
        #pragma unroll
        for (int j = 0; j < 4; ++j)
            #pragma unroll
            for (int hh = 0; hh < 2; ++hh)
                bf[j][hh] = *(const bf16x8*)(Wbase + (size_t)j * 16 * K
                                             + k0 + hh * 32);
        #pragma unroll
        for (int hh = 0; hh < 2; ++hh)
            #pragma unroll
            for (int i = 0; i < 2; ++i)
                #pragma unroll
                for (int j = 0; j < 4; ++j)
                    acc[i][j] = __builtin_amdgcn_mfma_f32_16x16x32_bf16(
                        af[i][hh], bf[j][hh], acc[i][j], 0, 0, 0);
    }

    if (MODE == 1 && n0 >= C_N) {        // kv tile: K cols 0..63, V 64..127
        #pragma unroll
        for (int i = 0; i < 2; ++i) {
            const int row0 = m0 + wm * 32 + i * 16 + quad * 4;
            #pragma unroll
            for (int j = 0; j < 4; ++j) {
                const int c2 = wn * 64 + j * 16 + ln;
                if (c2 >= 64) {
                    // vbt[b][d][t], 4 regs = 4 consecutive t
                    const int d = c2 - 64;
                    const int b = row0 >> 11;
                    const int t0 = row0 & 2047;
                    ushort4 pk;
                    pk.x = f2bf(acc[i][j][0]); pk.y = f2bf(acc[i][j][1]);
                    pk.z = f2bf(acc[i][j][2]); pk.w = f2bf(acc[i][j][3]);
                    *(ushort4*)&vbt[((size_t)b * 64 + d) * T_N + t0] = pk;
                } else {
                    #pragma unroll
                    for (int reg = 0; reg < 4; ++reg)
                        kb[(size_t)(row0 + reg) * 64 + c2] = f2bf(acc[i][j][reg]);
                }
            }
        }
        return;
    }

    #pragma unroll
    for (int i = 0; i < 2; ++i) {
        #pragma unroll
        for (int j = 0; j < 4; ++j) {
            const int col = n0 + wn * 64 + j * 16 + ln;
            const float bv = (MODE == 0) ? bias[col] : 0.f;
            #pragma unroll
            for (int reg = 0; reg < 4; ++reg) {
                const int row = m0 + wm * 32 + i * 16 + quad * 4 + reg;
                const float v = acc[i][j][reg] + bv;
                if (MODE == 0)
                    ((float*)Cout)[(size_t)row * C_N + col] = v;
                else
                    ((ushort*)Cout)[(size_t)row * C_N + col] = f2bf(v);
            }
        }
    }
}

// ---------------------------------------------------------------------------
// Flash causal MQA attention, bf16 MFMA, m=0 softmax, S^T formulation
// (round-6-verified math) — now BARRIER-FREE:
// kf/vf fragments load DIRECTLY from global (kb rows / pre-transposed vbt
// rows are lane-contiguous 16B), K/V reused 16x across heads -> L2-hot.
// LDS holds only the wave-private Ps round-trip (same-wave lgkmcnt, no sync).
// kf register-double-buffered: kt+1's K loads issue before kt's softmax, so
// QK's vmcnt wait leaves 16 loads in flight (AITER-style, never vmcnt(0)).
// Grid 32bh x 16 pairs = 512 blocks; block owns q-tiles A=p (kt<=p) and
// B=31-p (always): 33 subtile-computes per wave, uniform makespan.
// ---------------------------------------------------------------------------
__global__ __launch_bounds__(256, 2) void attn_mfma_kernel(
    const ushort* __restrict__ qb,
    const ushort* __restrict__ kb,    // [4096][64]
    const ushort* __restrict__ vbt,   // [2][64][2048]
    ushort* __restrict__ yb)
{
    __shared__ ushort Ps[4][16][72];   // per-wave [q][kk]

    const int bh = blockIdx.x;
    const int b = bh >> 4, h = bh & 15;
    const int p = blockIdx.y;          // 0..15
    const int qA0 = p * 64;            // light tile (active kt <= p)
    const int qB0 = (31 - p) * 64;     // heavy tile (always active)
    const int tid = threadIdx.x;
    const int wid = tid >> 6;
    const int lane = tid & 63;
    const int ln = lane & 15;
    const int quad = lane >> 4;

    // Q fragments, B-operand layout: Q[q=ln][d = half*32 + quad*8 + j]
    const ushort* qstrip = qb + (size_t)b * T_N * C_N + (size_t)h * T_N * HS_N;
    const size_t rB = (size_t)(qB0 + wid * 16 + ln) * HS_N;
    const size_t rA = (size_t)(qA0 + wid * 16 + ln) * HS_N;
    bf16x8 qfB[2], qfA[2];
    qfB[0] = *(const bf16x8*)(qstrip + rB + quad * 8);
    qfB[1] = *(const bf16x8*)(qstrip + rB + 32 + quad * 8);
    qfA[0] = *(const bf16x8*)(qstrip + rA + quad * 8);
    qfA[1] = *(const bf16x8*)(qstrip + rA + 32 + quad * 8);

    f32x4 oB[4], oA[4];
    float lB = 0.f, lA = 0.f;
    #pragma unroll
    for (int nt = 0; nt < 4; ++nt) {
        oB[nt] = (f32x4){0.f, 0.f, 0.f, 0.f};
        oA[nt] = (f32x4){0.f, 0.f, 0.f, 0.f};
    }

    // fragment source pointers (lane-fixed parts)
    const ushort* kfp = kb + (size_t)b * T_N * HS_N + (size_t)ln * HS_N
                        + quad * 8;                     // + (k0+nt*16)*64, +32
    const ushort* vfp = vbt + (size_t)b * HS_N * T_N + (size_t)ln * T_N
                        + quad * 8;                     // + nt*16*T + k0 + ks2*32

    const int nkt = 32 - p;

    bf16x8 kfc[4][2], kfn[4][2], vf[4][2];
    #pragma unroll
    for (int nt = 0; nt < 4; ++nt) {    // K fragments for kt=0
        kfc[nt][0] = *(const bf16x8*)(kfp + (size_t)(nt * 16) * HS_N);
        kfc[nt][1] = *(const bf16x8*)(kfp + (size_t)(nt * 16) * HS_N + 32);
    }

    // one 64-key tile for one 16-q subtile
    auto tile_compute = [&](const bf16x8* qf, f32x4* o, float& l,
                            int qt0, int k0) {
        const int qs0 = qt0 + wid * 16;
        const int qg = qs0 + ln;          // this lane's q-column
        f32x4 sc[4];
        #pragma unroll
        for (int nt = 0; nt < 4; ++nt) {
            sc[nt] = (f32x4){0.f, 0.f, 0.f, 0.f};
            sc[nt] = __builtin_amdgcn_mfma_f32_16x16x32_bf16(
                kfc[nt][0], qf[0], sc[nt], 0, 0, 0);
            sc[nt] = __builtin_amdgcn_mfma_f32_16x16x32_bf16(
                kfc[nt][1], qf[1], sc[nt], 0, 0, 0);
        }
        const bool dg = (k0 + 63 > qs0);
        #pragma unroll
        for (int nt = 0; nt < 4; ++nt) {
            ushort pk[4];
            #pragma unroll
            for (int reg = 0; reg < 4; ++reg) {
                const int key = k0 + nt * 16 + quad * 4 + reg;
                float sv = sc[nt][reg];
                if (dg && key > qg) sv = -1e30f;
                const float pe = __builtin_amdgcn_exp2f(sv);
                l += pe;
                pk[reg] = f2bf(pe);
            }
            *(uint2*)&Ps[wid][ln][nt * 16 + quad * 4] = *(const uint2*)pk;
        }
        #pragma unroll
        for (int ks2 = 0; ks2 < 2; ++ks2) {
            const bf16x8 pf = *(const bf16x8*)&Ps[wid][ln][ks2 * 32 + quad * 8];
            #pragma unroll
            for (int nt = 0; nt < 4; ++nt)
                o[nt] = __builtin_amdgcn_mfma_f32_16x16x32_bf16(
                    pf, vf[nt][ks2], o[nt], 0, 0, 0);
        }
    };

    for (int kt = 0; kt < nkt; ++kt) {
        const int k0 = kt * 64;
        // V fragments for THIS tile (consumed after softmax: latency hidden)
        #pragma unroll
        for (int nt = 0; nt < 4; ++nt) {
            vf[nt][0] = *(const bf16x8*)(vfp + (size_t)(nt * 16) * T_N + k0);
            vf[nt][1] = *(const bf16x8*)(vfp + (size_t)(nt * 16) * T_N + k0 + 32);
        }
        // K fragments for NEXT tile (consumed next iteration)
        if (kt + 1 < nkt) {
            const int kn = k0 + 64;
            #pragma unroll
            for (int nt = 0; nt < 4; ++nt) {
                kfn[nt][0] = *(const bf16x8*)(kfp + (size_t)(kn + nt * 16) * HS_N);
                kfn[nt][1] = *(const bf16x8*)(kfp + (size_t)(kn + nt * 16) * HS_N + 32);
            }
        }
        tile_compute(qfB, oB, lB, qB0, k0);
        if (kt <= p)
            tile_compute(qfA, oA, lA, qA0, k0);
        #pragma unroll
        for (int nt = 0; nt < 4; ++nt) {
            kfc[nt][0] = kfn[nt][0];
            kfc[nt][1] = kfn[nt][1];
        }
    }

    // epilogue: l lives per-lane at q=ln; reduce across quads, broadcast to
    // the C-layout row owners, write y = o / l
    #pragma unroll
    for (int t = 0; t < 2; ++t) {
        float l = t ? lA : lB;
        const f32x4* o = t ? oA : oB;
        const int qt0 = t ? qA0 : qB0;
        l += __shfl_xor(l, 16);
        l += __shfl_xor(l, 32);   // all lanes hold full l for q = ln
        #pragma unroll
        for (int reg = 0; reg < 4; ++reg) {
            const float inv = 1.0f / __shfl(l, quad * 4 + reg);
            const int qg = qt0 + wid * 16 + quad * 4 + reg;
            ushort* yrow = yb + (size_t)b * T_N * C_N + (size_t)qg * C_N
                           + h * HS_N;
            #pragma unroll
            for (int nt = 0; nt < 4; ++nt)
                yrow[nt * 16 + ln] = f2bf(o[nt][reg] * inv);
        }
    }
}

// ---------------------------------------------------------------------------
extern "C" void kernel_launch(void* const* d_in, const int* in_sizes, int n_in,
                              void* d_out, int out_size, void* d_ws, size_t ws_size,
                              hipStream_t stream) {
    const float* x  = (const float*)d_in[0];
    const float* Wk = (const float*)d_in[1];
    const float* Wv = (const float*)d_in[2];
    const float* Wq = (const float*)d_in[3];
    const float* Wp = (const float*)d_in[4];
    const float* bp = (const float*)d_in[5];
    float* out = (float*)d_out;

    ushort* xb   = (ushort*)d_ws;                     // [4096][1024]
    ushort* qb   = xb   + (size_t)M_N * C_N;          // [4096][1024]
    ushort* yb   = qb   + (size_t)M_N * C_N;          // [4096][1024]
    ushort* kbw  = yb   + (size_t)M_N * C_N;          // [4096][64]
    ushort* vbt  = kbw  + (size_t)M_N * HS_N;         // [2][64][2048]
    ushort* Wqb  = vbt  + (size_t)B_N * HS_N * T_N;   // [1024][1024] (scaled)
    ushort* Wkvb = Wqb  + (size_t)C_N * C_N;          // [128][1024], after Wq
    ushort* Wpb  = Wkvb + (size_t)128 * C_N;          // [1024][1024]

    cvt_all_kernel<<<1024, 256, 0, stream>>>(x, Wq, Wp, Wk, Wv,
                                             xb, Wqb, Wpb, Wkvb);

    // fused q + k + v projection: W' = [Wq(scaled); Wk; Wv] (1152 rows)
    // n-tiles 0..7 -> qb; tile 8 -> kbw (natural) + vbt (transposed)
    gemm_bf16<1, C_N><<<dim3(M_N / 64, (C_N + 128) / 128), 256, 0, stream>>>(
        xb, Wqb, nullptr, qb, kbw, vbt);

    // attention -> yb bf16 [4096][1024]; paired 64-row tiles (32bh x 16)
    attn_mfma_kernel<<<dim3(B_N * H_N, 16), 256, 0, stream>>>(qb, kbw, vbt, yb);

    // out = y @ Wp^T + bp -> fp32
    gemm_bf16<0, C_N><<<dim3(M_N / 64, C_N / 128), 256, 0, stream>>>(
        yb, Wpb, bp, out, nullptr, nullptr);
}

// Round 9
// 150.552 us; speedup vs baseline: 1.9660x; 1.9660x over previous
//
#include <hip/hip_runtime.h>
#include <cstddef>
#include <cstdint>

// Problem constants: B=2, T=2048, C=1024, H=16, hs=64
#define B_N 2
#define T_N 2048
#define C_N 1024
#define H_N 16
#define HS_N 64
#define M_N (B_N * T_N)   // 4096

typedef __attribute__((ext_vector_type(8))) short bf16x8;   // 8 bf16 = 4 VGPRs
typedef __attribute__((ext_vector_type(4))) float f32x4;

// 0.125 (hs^-0.5) * log2(e): folded into Wq so attention uses exp2 directly
#define QSCALE 0.18033688011112042f

__device__ __forceinline__ ushort f2bf(float f) {
    union { float f; uint32_t u; } v; v.f = f;
    uint32_t r = v.u + 0x7fffu + ((v.u >> 16) & 1u);   // round-nearest-even
    return (ushort)(r >> 16);
}
__device__ __forceinline__ ushort f2bf_trunc(float f) {   // P-matrix only
    union { float f; uint32_t u; } v; v.f = f;
    return (ushort)(v.u >> 16);
}

// async global->LDS, 16B per lane; lds base must be wave-uniform
#define GLL16(g, l)                                                         \
    __builtin_amdgcn_global_load_lds(                                       \
        (const __attribute__((address_space(1))) unsigned int*)(g),         \
        (__attribute__((address_space(3))) unsigned int*)(l), 16, 0, 0)

// ---------------------------------------------------------------------------
// Fused fp32->bf16 convert: x | Wq(*QSCALE) | Wp | Wk | Wv (one launch).
// ---------------------------------------------------------------------------
__global__ void cvt_all_kernel(const float* __restrict__ x,
                               const float* __restrict__ Wq,
                               const float* __restrict__ Wp,
                               const float* __restrict__ Wk,
                               const float* __restrict__ Wv,
                               ushort* __restrict__ xb,
                               ushort* __restrict__ Wqb,
                               ushort* __restrict__ Wpb,
                               ushort* __restrict__ Wkvb) {
    const int S0 = M_N * C_N / 4;
    const int S1 = S0 + C_N * C_N / 4;
    const int S2 = S1 + C_N * C_N / 4;
    const int S3 = S2 + HS_N * C_N / 4;
    const int S4 = S3 + HS_N * C_N / 4;
    const int stride = gridDim.x * blockDim.x;
    for (int i = blockIdx.x * blockDim.x + threadIdx.x; i < S4; i += stride) {
        const float* src; ushort* dst; int j; float sc = 1.f;
        if (i < S0)      { src = x;  dst = xb;   j = i; }
        else if (i < S1) { src = Wq; dst = Wqb;  j = i - S0; sc = QSCALE; }
        else if (i < S2) { src = Wp; dst = Wpb;  j = i - S1; }
        else if (i < S3) { src = Wk; dst = Wkvb; j = i - S2; }
        else             { src = Wv; dst = Wkvb + HS_N * C_N; j = i - S3; }
        const float4 f = ((const float4*)src)[j];
        ushort4 o;
        o.x = f2bf(f.x * sc); o.y = f2bf(f.y * sc);
        o.z = f2bf(f.z * sc); o.w = f2bf(f.w * sc);
        ((ushort4*)dst)[j] = o;
    }
}

// ---------------------------------------------------------------------------
// bf16 MFMA GEMM, BM=64, BN=128, BK=64, 256 threads (4 waves 2x2, 32x64 each)
// — the round-7 LDS/GLL16 structure (round-8's direct-global fragments were
// 16-segment gathers: transaction-bound, 2x slower; LDS staging is about
// gather->b128 conversion, not HBM reuse).
// NEW: XCD-aware block swizzle. Dispatch round-robins flat block id over the
// 8 XCDs, so flat%8 picks the XCD. Remap m_tile = (flat%8)*8 + (flat/8)%8,
// n_tile = flat/64: XCD k then only ever touches m-tiles [8k, 8k+8) -> its
// x footprint is 1MB (+ W ~2.25MB) and fits the 4MB per-XCD L2, turning the
// GLL16 drains from ~900-cyc HBM misses into ~200-cyc L2 hits.
// MODE 0: fp32 out + bias. MODE 1: bf16 out; 9th n-tile -> kb natural +
// vbt transposed [b][d][t] (packed ushort4 = 4 consecutive t).
// ---------------------------------------------------------------------------
template <int MODE>
__global__ __launch_bounds__(256, 2) void gemm_bf16(
    const ushort* __restrict__ A,   // [M][K] bf16
    const ushort* __restrict__ W,   // [Ntot][K] bf16
    const float* __restrict__ bias, // MODE 0 only
    void* __restrict__ Cout,        // [M][1024] fp32 (MODE 0) / bf16 (MODE 1)
    ushort* __restrict__ kb,        // MODE 1: [4096][64]
    ushort* __restrict__ vbt,       // MODE 1: [2][64][2048]
    int K)
{
    __shared__ ushort As[64 * 64];    // 8 KB
    __shared__ ushort Bs[128 * 64];   // 16 KB
    // XCD swizzle (gridDim.x == 64 == M/64)
    const int flat = blockIdx.x + (blockIdx.y << 6);
    const int m0 = (((flat & 7) << 3) | ((flat >> 3) & 7)) * 64;
    const int n0 = (flat >> 6) * 128;
    const int tid = threadIdx.x;
    const int wid = tid >> 6;
    const int lane = tid & 63;
    const int ln = lane & 15;
    const int quad = lane >> 4;
    const int wm = wid >> 1, wn = wid & 1;   // wave = rows wm*32+, cols wn*64+

    f32x4 acc[2][4];
    #pragma unroll
    for (int i = 0; i < 2; ++i)
        #pragma unroll
        for (int j = 0; j < 4; ++j)
            acc[i][j] = (f32x4){0.f, 0.f, 0.f, 0.f};

    const int srow = lane >> 3;          // 0..7 row within 8-row segment
    const int schk = (lane & 7) ^ srow;  // fetched chunk (row&7 == srow)

    for (int k0 = 0; k0 < K; k0 += 64) {
        __syncthreads();   // prior iteration's LDS reads complete
        #pragma unroll
        for (int t = 0; t < 2; ++t) {    // A: 8 segments of 8 rows
            const int seg = wid * 2 + t;
            GLL16(A + (size_t)(m0 + seg * 8 + srow) * K + k0 + schk * 8,
                  As + seg * 512);
        }
        #pragma unroll
        for (int t = 0; t < 4; ++t) {    // B: 16 segments of 8 rows
            const int seg = wid * 4 + t;
            GLL16(W + (size_t)(n0 + seg * 8 + srow) * K + k0 + schk * 8,
                  Bs + seg * 512);
        }
        __syncthreads();   // drains vmcnt (GLL16 counted there)

        #pragma unroll
        for (int hh = 0; hh < 2; ++hh) {
            bf16x8 af[2], bf[4];
            const int sw = ln & 7;
            #pragma unroll
            for (int i = 0; i < 2; ++i) {
                const int row = wm * 32 + i * 16 + ln;
                af[i] = *(const bf16x8*)&As[row * 64 + (((hh * 4 + quad) ^ sw) * 8)];
            }
            #pragma unroll
            for (int j = 0; j < 4; ++j) {
                const int row = wn * 64 + j * 16 + ln;
                bf[j] = *(const bf16x8*)&Bs[row * 64 + (((hh * 4 + quad) ^ sw) * 8)];
            }
            #pragma unroll
            for (int i = 0; i < 2; ++i)
                #pragma unroll
                for (int j = 0; j < 4; ++j)
                    acc[i][j] = __builtin_amdgcn_mfma_f32_16x16x32_bf16(
                        af[i], bf[j], acc[i][j], 0, 0, 0);
        }
    }

    if (MODE == 1 && n0 >= C_N) {        // kv tile: K cols 0..63, V 64..127
        #pragma unroll
        for (int i = 0; i < 2; ++i) {
            const int row0 = m0 + wm * 32 + i * 16 + quad * 4;
            #pragma unroll
            for (int j = 0; j < 4; ++j) {
                const int c2 = wn * 64 + j * 16 + ln;
                if (c2 >= 64) {
                    // vbt[b][d][t], 4 regs = 4 consecutive t
                    const int d = c2 - 64;
                    const int b = row0 >> 11;
                    const int t0 = row0 & 2047;
                    ushort4 pk;
                    pk.x = f2bf(acc[i][j][0]); pk.y = f2bf(acc[i][j][1]);
                    pk.z = f2bf(acc[i][j][2]); pk.w = f2bf(acc[i][j][3]);
                    *(ushort4*)&vbt[((size_t)b * 64 + d) * T_N + t0] = pk;
                } else {
                    #pragma unroll
                    for (int reg = 0; reg < 4; ++reg)
                        kb[(size_t)(row0 + reg) * 64 + c2] = f2bf(acc[i][j][reg]);
                }
            }
        }
        return;
    }

    #pragma unroll
    for (int i = 0; i < 2; ++i) {
        #pragma unroll
        for (int j = 0; j < 4; ++j) {
            const int col = n0 + wn * 64 + j * 16 + ln;
            const float bv = (MODE == 0) ? bias[col] : 0.f;
            #pragma unroll
            for (int reg = 0; reg < 4; ++reg) {
                const int row = m0 + wm * 32 + i * 16 + quad * 4 + reg;
                const float v = acc[i][j][reg] + bv;
                if (MODE == 0)
                    ((float*)Cout)[(size_t)row * C_N + col] = v;
                else
                    ((ushort*)Cout)[(size_t)row * C_N + col] = f2bf(v);
            }
        }
    }
}

// ---------------------------------------------------------------------------
// Flash causal MQA attention — round-6 version verbatim (best measured:
// 45.5 us), plus truncating bf16 pack for P (2 VALU/elem off the softmax;
// P in [0,1], added error ~2^-9 rel, 4x threshold headroom).
// S^T formulation; K/V staged via LDS (b128-clean); 512 blocks (2/CU).
// ---------------------------------------------------------------------------
__global__ __launch_bounds__(256, 2) void attn_mfma_kernel(
    const ushort* __restrict__ qb,
    const ushort* __restrict__ kb,    // [4096][64]
    const ushort* __restrict__ vbt,   // [2][64][2048]
    ushort* __restrict__ yb)
{
    __shared__ ushort Ks[64][72];      // [kk][d]
    __shared__ ushort Vt[64][72];      // [d][kk]
    __shared__ ushort Ps[4][16][72];   // per-wave [q][kk]

    const int bh = blockIdx.x;
    const int b = bh >> 4, h = bh & 15;
    const int p = blockIdx.y;          // 0..15
    const int qA0 = p * 64;            // light tile (active kt <= p)
    const int qB0 = (31 - p) * 64;     // heavy tile (always active)
    const int tid = threadIdx.x;
    const int wid = tid >> 6;
    const int lane = tid & 63;
    const int ln = lane & 15;
    const int quad = lane >> 4;

    // Q fragments, B-operand layout: Q[q=ln][d = half*32 + quad*8 + j]
    const ushort* qstrip = qb + (size_t)b * T_N * C_N + (size_t)h * T_N * HS_N;
    const size_t rB = (size_t)(qB0 + wid * 16 + ln) * HS_N;
    const size_t rA = (size_t)(qA0 + wid * 16 + ln) * HS_N;
    bf16x8 qfB[2], qfA[2];
    qfB[0] = *(const bf16x8*)(qstrip + rB + quad * 8);
    qfB[1] = *(const bf16x8*)(qstrip + rB + 32 + quad * 8);
    qfA[0] = *(const bf16x8*)(qstrip + rA + quad * 8);
    qfA[1] = *(const bf16x8*)(qstrip + rA + 32 + quad * 8);

    f32x4 oB[4], oA[4];
    float lB = 0.f, lA = 0.f;
    #pragma unroll
    for (int nt = 0; nt < 4; ++nt) {
        oB[nt] = (f32x4){0.f, 0.f, 0.f, 0.f};
        oA[nt] = (f32x4){0.f, 0.f, 0.f, 0.f};
    }

    const ushort* kbase = kb + (size_t)b * T_N * HS_N;
    const ushort* vtbase = vbt + (size_t)b * HS_N * T_N;
    const int rs = tid >> 3;   // 0..31 staging row
    const int cs = tid & 7;    // 0..7 staging 16B chunk

    int4 kc0, kc1, vc0, vc1;
    {   // prologue: k-tile 0
        kc0 = *(const int4*)(kbase + (size_t)rs * HS_N + cs * 8);
        kc1 = *(const int4*)(kbase + (size_t)(rs + 32) * HS_N + cs * 8);
        vc0 = *(const int4*)(vtbase + (size_t)rs * T_N + cs * 8);
        vc1 = *(const int4*)(vtbase + (size_t)(rs + 32) * T_N + cs * 8);
    }

    bf16x8 kf[4][2], vf[4][2];

    // one 64-key tile for one 16-q subtile
    auto tile_compute = [&](const bf16x8* qf, f32x4* o, float& l,
                            int qt0, int k0) {
        const int qs0 = qt0 + wid * 16;
        const int qg = qs0 + ln;          // this lane's q-column
        f32x4 sc[4];
        #pragma unroll
        for (int nt = 0; nt < 4; ++nt) {
            sc[nt] = (f32x4){0.f, 0.f, 0.f, 0.f};
            sc[nt] = __builtin_amdgcn_mfma_f32_16x16x32_bf16(
                kf[nt][0], qf[0], sc[nt], 0, 0, 0);
            sc[nt] = __builtin_amdgcn_mfma_f32_16x16x32_bf16(
                kf[nt][1], qf[1], sc[nt], 0, 0, 0);
        }
        const bool dg = (k0 + 63 > qs0);
        #pragma unroll
        for (int nt = 0; nt < 4; ++nt) {
            ushort pk[4];
            #pragma unroll
            for (int reg = 0; reg < 4; ++reg) {
                const int key = k0 + nt * 16 + quad * 4 + reg;
                float sv = sc[nt][reg];
                if (dg && key > qg) sv = -1e30f;
                const float pe = __builtin_amdgcn_exp2f(sv);
                l += pe;
                pk[reg] = f2bf_trunc(pe);
            }
            *(uint2*)&Ps[wid][ln][nt * 16 + quad * 4] = *(const uint2*)pk;
        }
        #pragma unroll
        for (int ks2 = 0; ks2 < 2; ++ks2) {
            const bf16x8 pf = *(const bf16x8*)&Ps[wid][ln][ks2 * 32 + quad * 8];
            #pragma unroll
            for (int nt = 0; nt < 4; ++nt)
                o[nt] = __builtin_amdgcn_mfma_f32_16x16x32_bf16(
                    pf, vf[nt][ks2], o[nt], 0, 0, 0);
        }
    };

    const int nkt = 32 - p;
    for (int kt = 0; kt < nkt; ++kt) {
        const int k0 = kt * 64;
        __syncthreads();   // prior iteration's LDS reads complete
        *(int4*)&Ks[rs][cs * 8] = kc0;
        *(int4*)&Ks[rs + 32][cs * 8] = kc1;
        *(int4*)&Vt[rs][cs * 8] = vc0;
        *(int4*)&Vt[rs + 32][cs * 8] = vc1;
        __syncthreads();
        if (kt + 1 < nkt) {   // prefetch next k-tile into regs
            const int kn = k0 + 64;
            kc0 = *(const int4*)(kbase + (size_t)(kn + rs) * HS_N + cs * 8);
            kc1 = *(const int4*)(kbase + (size_t)(kn + rs + 32) * HS_N + cs * 8);
            vc0 = *(const int4*)(vtbase + (size_t)rs * T_N + kn + cs * 8);
            vc1 = *(const int4*)(vtbase + (size_t)(rs + 32) * T_N + kn + cs * 8);
        }
        // shared K/V fragments for this k-tile (read once, both subtiles)
        #pragma unroll
        for (int nt = 0; nt < 4; ++nt) {
            kf[nt][0] = *(const bf16x8*)&Ks[nt * 16 + ln][quad * 8];
            kf[nt][1] = *(const bf16x8*)&Ks[nt * 16 + ln][32 + quad * 8];
            vf[nt][0] = *(const bf16x8*)&Vt[nt * 16 + ln][quad * 8];
            vf[nt][1] = *(const bf16x8*)&Vt[nt * 16 + ln][32 + quad * 8];
        }
        tile_compute(qfB, oB, lB, qB0, k0);
        if (kt <= p)
            tile_compute(qfA, oA, lA, qA0, k0);
    }

    // epilogue: l lives per-lane at q=ln; reduce across quads, broadcast to
    // the C-layout row owners, write y = o / l
    #pragma unroll
    for (int t = 0; t < 2; ++t) {
        float l = t ? lA : lB;
        const f32x4* o = t ? oA : oB;
        const int qt0 = t ? qA0 : qB0;
        l += __shfl_xor(l, 16);
        l += __shfl_xor(l, 32);   // all lanes hold full l for q = ln
        #pragma unroll
        for (int reg = 0; reg < 4; ++reg) {
            const float inv = 1.0f / __shfl(l, quad * 4 + reg);
            const int qg = qt0 + wid * 16 + quad * 4 + reg;
            ushort* yrow = yb + (size_t)b * T_N * C_N + (size_t)qg * C_N
                           + h * HS_N;
            #pragma unroll
            for (int nt = 0; nt < 4; ++nt)
                yrow[nt * 16 + ln] = f2bf(o[nt][reg] * inv);
        }
    }
}

// ---------------------------------------------------------------------------
extern "C" void kernel_launch(void* const* d_in, const int* in_sizes, int n_in,
                              void* d_out, int out_size, void* d_ws, size_t ws_size,
                              hipStream_t stream) {
    const float* x  = (const float*)d_in[0];
    const float* Wk = (const float*)d_in[1];
    const float* Wv = (const float*)d_in[2];
    const float* Wq = (const float*)d_in[3];
    const float* Wp = (const float*)d_in[4];
    const float* bp = (const float*)d_in[5];
    float* out = (float*)d_out;

    ushort* xb   = (ushort*)d_ws;                     // [4096][1024]
    ushort* qb   = xb   + (size_t)M_N * C_N;          // [4096][1024]
    ushort* yb   = qb   + (size_t)M_N * C_N;          // [4096][1024]
    ushort* kbw  = yb   + (size_t)M_N * C_N;          // [4096][64]
    ushort* vbt  = kbw  + (size_t)M_N * HS_N;         // [2][64][2048]
    ushort* Wqb  = vbt  + (size_t)B_N * HS_N * T_N;   // [1024][1024] (scaled)
    ushort* Wkvb = Wqb  + (size_t)C_N * C_N;          // [128][1024], after Wq
    ushort* Wpb  = Wkvb + (size_t)128 * C_N;          // [1024][1024]

    cvt_all_kernel<<<1024, 256, 0, stream>>>(x, Wq, Wp, Wk, Wv,
                                             xb, Wqb, Wpb, Wkvb);

    // fused q + k + v projection: W' = [Wq(scaled); Wk; Wv] (1152 rows)
    // n-tiles 0..7 -> qb; tile 8 -> kbw (natural) + vbt (transposed)
    gemm_bf16<1><<<dim3(M_N / 64, (C_N + 128) / 128), 256, 0, stream>>>(
        xb, Wqb, nullptr, qb, kbw, vbt, C_N);

    // attention -> yb bf16 [4096][1024]; paired 64-row tiles (32bh x 16)
    attn_mfma_kernel<<<dim3(B_N * H_N, 16), 256, 0, stream>>>(qb, kbw, vbt, yb);

    // out = y @ Wp^T + bp -> fp32
    gemm_bf16<0><<<dim3(M_N / 64, C_N / 128), 256, 0, stream>>>(
        yb, Wpb, bp, out, nullptr, nullptr, C_N);
}